// Round 3
// baseline (262.573 us; speedup 1.0000x reference)
//
#include <hip/hip_runtime.h>

#define NUM_REGIONS 32
#define NBINS 33                        // regions 0..32 (0 dropped in the loss)
#define BATCH 4
#define DHW (160*192*192)               // 5,898,240 per volume, divisible by 4
#define NVEC_PER_BATCH (DHW/4)          // 1,474,560 float4 vectors per batch
#define BLOCKS_PER_BATCH 384
#define NBLOCKS (BATCH*BLOCKS_PER_BATCH)                 // 1536 = 6 per CU, one generation
#define VEC_PER_BLOCK (NVEC_PER_BATCH/BLOCKS_PER_BATCH)  // 3840
#define ITERS (VEC_PER_BLOCK/256)                        // 15 per thread
#define COL_STRIDE 129                  // 129 % 32 == 1 -> bank = (bin+col)%32
#define EPS 1e-8f

// ---------------------------------------------------------------------------
// Kernel 1: per-thread-pair privatized LDS histogram via fire-and-forget
// ds_add_f32 atomics (no return -> no dependency chain, unlike += RMW).
// col = tid>>1: two lanes share a column but NEVER the same address in one
// instruction unless bins match (rare; hardware serializes correctly).
// Packed accumulate V = sum(sigmoid) + 256*count; count = floor(V/256) at
// reduce (per-column count <= 120, fractional part < 120 << 256 -> exact).
// ws layout: ws[0..132) = xs sums, ws[132..264) = counts (as float).
// ---------------------------------------------------------------------------
__global__ __launch_bounds__(256) void region_sums_kernel(
    const float* __restrict__ x,
    const int*   __restrict__ seg,
    float*       __restrict__ ws)
{
    __shared__ float hist[NBINS * COL_STRIDE];   // 33*129*4 = 17,028 B
    __shared__ float part_xs [8][NBINS];
    __shared__ float part_cnt[8][NBINS];

    const int tid = threadIdx.x;
    const int col = tid >> 1;

    for (int i = tid; i < NBINS * COL_STRIDE; i += 256) hist[i] = 0.0f;
    __syncthreads();

    const int batch = blockIdx.x / BLOCKS_PER_BATCH;
    const int local = blockIdx.x - batch * BLOCKS_PER_BATCH;
    const int vbase = batch * NVEC_PER_BATCH + local * VEC_PER_BLOCK + tid;

    const float4* __restrict__ xv4 = (const float4*)x;
    const int4*   __restrict__ sv4 = (const int4*)seg;

    // 2-deep rolling prefetch with NAMED registers (no runtime-indexed arrays)
    float4 xA = xv4[vbase];       int4 sA = sv4[vbase];
    float4 xB = xv4[vbase + 256]; int4 sB = sv4[vbase + 256];

    for (int k = 0; k < ITERS; ++k) {
        // prefetch k+2 (clamped: last two iters re-load vec ITERS-1, harmless)
        int kn = (k + 2 < ITERS) ? (k + 2) : (ITERS - 1);
        float4 xN = xv4[vbase + kn * 256];
        int4   sN = sv4[vbase + kn * 256];

        float p0 = __fdividef(1.0f, 1.0f + __expf(-xA.x)) + 256.0f;
        float p1 = __fdividef(1.0f, 1.0f + __expf(-xA.y)) + 256.0f;
        float p2 = __fdividef(1.0f, 1.0f + __expf(-xA.z)) + 256.0f;
        float p3 = __fdividef(1.0f, 1.0f + __expf(-xA.w)) + 256.0f;

        // fire-and-forget LDS atomics: ds_add_f32, no return, no chain
        atomicAdd(&hist[sA.x * COL_STRIDE + col], p0);
        atomicAdd(&hist[sA.y * COL_STRIDE + col], p1);
        atomicAdd(&hist[sA.z * COL_STRIDE + col], p2);
        atomicAdd(&hist[sA.w * COL_STRIDE + col], p3);

        xA = xB; sA = sB; xB = xN; sB = sN;
    }
    __syncthreads();

    // Parallel reduce: 256 threads = 8 groups x 32 bins (bins 1..32; bin 0
    // is dropped by the loss). Group g sums 16 columns of its bin.
    // Read banks: (bin + g*16 + j) % 32 -> all 64 lanes distinct, conflict-free.
    {
        const int bin = (tid & 31) + 1;
        const int g   = tid >> 5;
        float xs = 0.0f, cnt = 0.0f;
        #pragma unroll
        for (int j = 0; j < 16; ++j) {
            float V = hist[bin * COL_STRIDE + g * 16 + j];
            float c = floorf(V * (1.0f / 256.0f));
            cnt += c;
            xs  += V - 256.0f * c;
        }
        part_xs [g][bin] = xs;
        part_cnt[g][bin] = cnt;
    }
    __syncthreads();

    if (tid < 32) {
        const int bin = tid + 1;
        float xs = 0.0f, cnt = 0.0f;
        #pragma unroll
        for (int g = 0; g < 8; ++g) {
            xs  += part_xs [g][bin];
            cnt += part_cnt[g][bin];
        }
        atomicAdd(&ws[batch * NBINS + bin], xs);
        atomicAdd(&ws[BATCH * NBINS + batch * NBINS + bin], cnt);
    }
}

// ---------------------------------------------------------------------------
// Kernel 2: dice + mean epilogue. One wave; lane r handles region r (1..32).
// ---------------------------------------------------------------------------
__global__ void region_dice_final_kernel(
    const float* __restrict__ ws,
    float*       __restrict__ out)
{
    const int lane = threadIdx.x;   // 0..63
    float loss_sum = 0.0f;

    for (int b = 0; b < BATCH; ++b) {
        bool  valid = false;
        float dice  = 0.0f;
        if (lane >= 1 && lane <= NUM_REGIONS) {
            float xs  = ws[b * NBINS + lane];
            float cnt = ws[BATCH * NBINS + b * NBINS + lane];
            valid = (cnt > 0.0f);
            if (valid) dice = 2.0f * xs / (xs + cnt + EPS);
        }
        unsigned long long m = __ballot(valid);
        int n_valid = __popcll(m);

        float s = dice;
        #pragma unroll
        for (int off = 32; off >= 1; off >>= 1) s += __shfl_down(s, off);

        float mean_dice = s / (float)((n_valid > 1) ? n_valid : 1);
        float loss_b    = (n_valid > 0) ? (1.0f - mean_dice) : 1.0f;
        loss_sum += loss_b;
    }

    if (lane == 0) out[0] = loss_sum * (1.0f / BATCH);
}

extern "C" void kernel_launch(void* const* d_in, const int* in_sizes, int n_in,
                              void* d_out, int out_size, void* d_ws, size_t ws_size,
                              hipStream_t stream)
{
    const float* x   = (const float*)d_in[0];
    const int*   seg = (const int*)d_in[1];
    float*       ws  = (float*)d_ws;

    // d_ws is poisoned with 0xAA before every timed launch — zero the bins.
    hipMemsetAsync(d_ws, 0, 2 * BATCH * NBINS * sizeof(float), stream);

    region_sums_kernel<<<NBLOCKS, 256, 0, stream>>>(x, seg, ws);
    region_dice_final_kernel<<<1, 64, 0, stream>>>(ws, (float*)d_out);
}

// Round 4
// 213.048 us; speedup vs baseline: 1.2325x; 1.2325x over previous
//
#include <hip/hip_runtime.h>

#define NUM_REGIONS 32
#define NBINS 33                        // regions 0..32 (0 dropped in the loss)
#define BATCH 4
#define DHW (160*192*192)               // 5,898,240 per volume, divisible by 4
#define NVEC_PER_BATCH (DHW/4)          // 1,474,560 float4 vectors per batch
#define BLOCKS_PER_BATCH 384
#define NBLOCKS (BATCH*BLOCKS_PER_BATCH)                 // 1536 = 6 per CU
#define VEC_PER_BLOCK (NVEC_PER_BATCH/BLOCKS_PER_BATCH)  // 3840
#define ITERS (VEC_PER_BLOCK/256)                        // 15 per thread
#define COL_STRIDE 129                  // 129 % 32 == 1 -> bank = (bin+col)%32
#define QSCALE 262144.0f                // 2^18 fixed-point scale for sigmoid
#define INV_QSCALE (1.0f/262144.0f)
#define CNT_SHIFT 25
#define XS_MASK ((1u<<CNT_SHIFT)-1u)
#define EPS 1e-8f

// ---------------------------------------------------------------------------
// Kernel 1: per-thread-pair privatized LDS histogram via INTEGER ds_add_u32
// atomics (bank-parallel LDS integer ALUs — FP LDS atomics measured ~3.5
// cy/lane serialized on gfx950, R1/R3; int path is the HW histogram path).
// One packed u32 atomic per element:
//   packed = round(sigmoid(x) * 2^18)  +  (1 << 25)
//   bits 0..24  : fixed-point xs sum   (max 120 * 2^18 = 31.5M < 2^25)
//   bits 25..31 : element count        (max 120 per (bin,col) < 128)
// Exactly 120 elements land in each column (2 threads x 15 iters x 4 comps),
// so both fields are overflow-safe even if all hit one bin.
// ws layout: ws[0..132) = xs sums (float), ws[132..264) = counts (float).
// ---------------------------------------------------------------------------
__global__ __launch_bounds__(256) void region_sums_kernel(
    const float* __restrict__ x,
    const int*   __restrict__ seg,
    float*       __restrict__ ws)
{
    __shared__ unsigned int hist[NBINS * COL_STRIDE];   // 33*129*4 = 17,028 B
    __shared__ float part_xs [8][NBINS];
    __shared__ float part_cnt[8][NBINS];

    const int tid = threadIdx.x;
    const int col = tid >> 1;

    for (int i = tid; i < NBINS * COL_STRIDE; i += 256) hist[i] = 0u;
    __syncthreads();

    const int batch = blockIdx.x / BLOCKS_PER_BATCH;
    const int local = blockIdx.x - batch * BLOCKS_PER_BATCH;
    const int vbase = batch * NVEC_PER_BATCH + local * VEC_PER_BLOCK + tid;

    const float4* __restrict__ xv4 = (const float4*)x;
    const int4*   __restrict__ sv4 = (const int4*)seg;

    // 2-deep rolling prefetch with NAMED registers (no runtime-indexed arrays)
    float4 xA = xv4[vbase];       int4 sA = sv4[vbase];
    float4 xB = xv4[vbase + 256]; int4 sB = sv4[vbase + 256];

    for (int k = 0; k < ITERS; ++k) {
        int kn = (k + 2 < ITERS) ? (k + 2) : (ITERS - 1);
        float4 xN = xv4[vbase + kn * 256];
        int4   sN = sv4[vbase + kn * 256];

        float p0 = __fdividef(1.0f, 1.0f + __expf(-xA.x));
        float p1 = __fdividef(1.0f, 1.0f + __expf(-xA.y));
        float p2 = __fdividef(1.0f, 1.0f + __expf(-xA.z));
        float p3 = __fdividef(1.0f, 1.0f + __expf(-xA.w));

        // fixed-point pack: count in bits 25..31, xs (2^-18 units) in 0..24
        unsigned q0 = (unsigned)(fmaf(p0, QSCALE, 0.5f)) + (1u << CNT_SHIFT);
        unsigned q1 = (unsigned)(fmaf(p1, QSCALE, 0.5f)) + (1u << CNT_SHIFT);
        unsigned q2 = (unsigned)(fmaf(p2, QSCALE, 0.5f)) + (1u << CNT_SHIFT);
        unsigned q3 = (unsigned)(fmaf(p3, QSCALE, 0.5f)) + (1u << CNT_SHIFT);

        atomicAdd(&hist[sA.x * COL_STRIDE + col], q0);
        atomicAdd(&hist[sA.y * COL_STRIDE + col], q1);
        atomicAdd(&hist[sA.z * COL_STRIDE + col], q2);
        atomicAdd(&hist[sA.w * COL_STRIDE + col], q3);

        xA = xB; sA = sB; xB = xN; sB = sN;
    }
    __syncthreads();

    // Parallel reduce: 8 groups x 32 bins (bin 0 dropped); group g sums 16
    // of the 128 columns. Banks (bin + g*16 + j) % 32 -> conflict-free.
    {
        const int bin = (tid & 31) + 1;
        const int g   = tid >> 5;
        float xs = 0.0f, cnt = 0.0f;
        #pragma unroll
        for (int j = 0; j < 16; ++j) {
            unsigned V = hist[bin * COL_STRIDE + g * 16 + j];
            cnt += (float)(V >> CNT_SHIFT);
            xs  += (float)(V & XS_MASK);
        }
        part_xs [g][bin] = xs;
        part_cnt[g][bin] = cnt;
    }
    __syncthreads();

    if (tid < 32) {
        const int bin = tid + 1;
        float xs = 0.0f, cnt = 0.0f;
        #pragma unroll
        for (int g = 0; g < 8; ++g) {
            xs  += part_xs [g][bin];
            cnt += part_cnt[g][bin];
        }
        atomicAdd(&ws[batch * NBINS + bin], xs * INV_QSCALE);
        atomicAdd(&ws[BATCH * NBINS + batch * NBINS + bin], cnt);
    }
}

// ---------------------------------------------------------------------------
// Kernel 2: dice + mean epilogue. One wave; lane r handles region r (1..32).
// ---------------------------------------------------------------------------
__global__ void region_dice_final_kernel(
    const float* __restrict__ ws,
    float*       __restrict__ out)
{
    const int lane = threadIdx.x;   // 0..63
    float loss_sum = 0.0f;

    for (int b = 0; b < BATCH; ++b) {
        bool  valid = false;
        float dice  = 0.0f;
        if (lane >= 1 && lane <= NUM_REGIONS) {
            float xs  = ws[b * NBINS + lane];
            float cnt = ws[BATCH * NBINS + b * NBINS + lane];
            valid = (cnt > 0.0f);
            if (valid) dice = 2.0f * xs / (xs + cnt + EPS);
        }
        unsigned long long m = __ballot(valid);
        int n_valid = __popcll(m);

        float s = dice;
        #pragma unroll
        for (int off = 32; off >= 1; off >>= 1) s += __shfl_down(s, off);

        float mean_dice = s / (float)((n_valid > 1) ? n_valid : 1);
        float loss_b    = (n_valid > 0) ? (1.0f - mean_dice) : 1.0f;
        loss_sum += loss_b;
    }

    if (lane == 0) out[0] = loss_sum * (1.0f / BATCH);
}

extern "C" void kernel_launch(void* const* d_in, const int* in_sizes, int n_in,
                              void* d_out, int out_size, void* d_ws, size_t ws_size,
                              hipStream_t stream)
{
    const float* x   = (const float*)d_in[0];
    const int*   seg = (const int*)d_in[1];
    float*       ws  = (float*)d_ws;

    // d_ws is poisoned with 0xAA before every timed launch — zero the bins.
    hipMemsetAsync(d_ws, 0, 2 * BATCH * NBINS * sizeof(float), stream);

    region_sums_kernel<<<NBLOCKS, 256, 0, stream>>>(x, seg, ws);
    region_dice_final_kernel<<<1, 64, 0, stream>>>(ws, (float*)d_out);
}